// Round 15
// baseline (363.886 us; speedup 1.0000x reference)
//
#include <hip/hip_runtime.h>
#include <hip/hip_bf16.h>
#include <math.h>
#include <stdint.h>

typedef __attribute__((ext_vector_type(8))) short bf16x8;
typedef __attribute__((ext_vector_type(4))) float f32x4;

__device__ __forceinline__ uint32_t pack2(float a, float b) {
    union { __hip_bfloat162 h2; uint32_t u; } c;
    c.h2 = __float22bfloat162_rn(make_float2(a, b));   // v_cvt_pk_bf16_f32
    return c.u;
}
__device__ __forceinline__ unsigned short f2bf(float f) {
    union { __hip_bfloat16 h; unsigned short u; } c;
    c.h = __float2bfloat16(f);
    return c.u;
}
__device__ __forceinline__ float bf2f(unsigned short h) {
    union { uint32_t u; float f; } c; c.u = ((uint32_t)h) << 16;
    return c.f;
}
__device__ __forceinline__ float silu_f(float x) {
    return x / (1.0f + __expf(-x));
}

// Uniform cardinal cubic B-spline bases on grid g_i = -2.2 + 0.4*i.
// Identical to the reference Cox-de-Boor recursion on this uniform grid.
__device__ __forceinline__ void bspline8(float x, float* __restrict__ b) {
    const float tt = (x + 2.2f) * 2.5f;
#pragma unroll
    for (int v = 0; v < 8; ++v) {
        float y = fabsf(tt - (float)(v + 2));
        float p = fmaxf(2.0f - y, 0.0f);
        float q = fmaxf(1.0f - y, 0.0f);
        b[v] = (p * p * p - 4.0f * q * q * q) * (1.0f / 6.0f);
    }
}

// ---------------------------------------------------------------------------
// prep kernels: weights -> fragment-contiguous bf16 [tile][wc2][nt4][ks4][l64][e8]
//   col = wc*64 + nt*16 + (l&15);  k = tile*128 + ks*32 + (l>>4)*8 + e
// ---------------------------------------------------------------------------
__global__ __launch_bounds__(256) void prep_wbf(const float* __restrict__ ftw,
                                                unsigned short* __restrict__ WbF) {
    const int idx = blockIdx.x * 256 + threadIdx.x;   // 98304 = 6*16384
    const int e = idx & 7, l = (idx >> 3) & 63, ks = (idx >> 9) & 3;
    const int nt = (idx >> 11) & 3, wc = (idx >> 13) & 1, tile = idx >> 14;
    const int col = wc * 64 + nt * 16 + (l & 15);
    const int k = tile * 128 + ks * 32 + (l >> 4) * 8 + e;
    WbF[idx] = f2bf(ftw[(size_t)col * 768 + k]);
}

__global__ __launch_bounds__(256) void prep_bpf(const float* __restrict__ bw,
                                                const float* __restrict__ sw,
                                                unsigned short* __restrict__ BpF) {
    const int idx = blockIdx.x * 256 + threadIdx.x;   // 524288 = 32*16384
    const int e = idx & 7, l = (idx >> 3) & 63, ks = (idx >> 9) & 3;
    const int nt = (idx >> 11) & 3, wc = (idx >> 13) & 1, jb = idx >> 14;
    const int col = wc * 64 + nt * 16 + (l & 15);
    const int k = jb * 128 + ks * 32 + (l >> 4) * 8 + e;
    const int f = k >> 4, v = k & 15;
    float val = 0.f;
    if (v == 0) val = bw[col * 256 + f];
    else if (v <= 8) val = sw[(size_t)(col * 256 + f) * 8 + (v - 1)];
    BpF[idx] = f2bf(val);
}

// ---------------------------------------------------------------------------
// FUSED with PRODUCER/CONSUMER WAVE SPECIALIZATION.  BM=64, grid 512
// (2 blocks/CU, LDS 64 KB), block 512 = 8 waves:
//   waves 0-3 CONSUMERS: tile 32r x 64c, B frag-contiguous global->reg,
//                        8 ds_read_b128 + 32 MFMA per phase.
//   waves 4-7 PRODUCERS: ph1 stream A (lane-contiguous 1KB loads -> cvt ->
//                        swizzled LDS dbuf); ph2 spline-expand phi dbuf.
// Producer VALU overlaps consumer MFMA+DS within the block; ONE barrier
// per phase; no vmcnt drains anywhere.
// LDS: [0,32K) A/phi double buffer (2x16K) | [32K,64K) smHT [256][64] bf16.
// ---------------------------------------------------------------------------
__global__ __launch_bounds__(512, 4) void kan_fused(
        const float* __restrict__ stm, const float* __restrict__ nstm,
        const unsigned short* __restrict__ WbF, const float* __restrict__ bias,
        const unsigned short* __restrict__ BpF,
        const float* __restrict__ w2b, const float* __restrict__ w2s,
        float* __restrict__ out) {
    __shared__ alignas(16) char lds[65536];
    char* buf0 = lds;
    char* buf1 = lds + 16384;
    char* smHT = lds + 32768;     // H^T [256 feat][64 rows] bf16, swizzled

    const int r0 = blockIdx.x * 64;
    const int t = threadIdx.x;
    const int l = t & 63, w = t >> 6;
    const int fr = l & 15, h = l >> 4;
    const bool cons = (w < 4);
    const int wr = (w >> 1) & 1, wc = w & 1;   // consumer: 2x2 of 32r x 64c
    const int p = w & 3;                        // producer id 0..3

    f32x4 acc[2][4];
#pragma unroll
    for (int mt = 0; mt < 2; ++mt)
#pragma unroll
        for (int nt = 0; nt < 4; ++nt) acc[mt][nt] = (f32x4){0.f, 0.f, 0.f, 0.f};

    bf16x8 bf[4][4];   // B fragments [nt][ks] -- static indexing only

#define LOADF(PTR, TILE)                                                       \
    {                                                                          \
        const unsigned short* __restrict__ fb =                                \
            (PTR) + (size_t)(TILE) * 16384 + wc * 8192 + l * 8;                \
        _Pragma("unroll") for (int nt = 0; nt < 4; ++nt)                       \
            _Pragma("unroll") for (int ks = 0; ks < 4; ++ks)                   \
                bf[nt][ks] = *reinterpret_cast<const bf16x8*>(                 \
                    fb + nt * 2048 + ks * 512);                                \
    }

// producer: stage A tile T (64r x 128k fp32 -> bf16) into DST, swizzled.
// instr i covers 2 rows, lane-contiguous 1KB global reads.
#define STAGE_A(DST, T)                                                        \
    {                                                                          \
        const float* __restrict__ Ap = ((T) >= 6) ? nstm : stm;                \
        const int kk = ((T) % 6) * 128;                                        \
        float4 fv[8];                                                          \
        _Pragma("unroll") for (int i = 0; i < 8; ++i) {                        \
            const int row = p * 16 + i * 2 + (l >> 5);                         \
            fv[i] = *reinterpret_cast<const float4*>(                          \
                &Ap[(size_t)(r0 + row) * 768 + kk + (l & 31) * 4]);            \
        }                                                                      \
        _Pragma("unroll") for (int i = 0; i < 8; ++i) {                        \
            const int row = p * 16 + i * 2 + (l >> 5);                         \
            const uint32_t c = (uint32_t)((l & 31) >> 1);                      \
            const uint32_t dst = (uint32_t)row * 256u +                        \
                ((c ^ (uint32_t)(row & 15)) << 4) + (uint32_t)(l & 1) * 8u;    \
            int2 v;                                                            \
            v.x = (int)pack2(fv[i].x, fv[i].y);                                \
            v.y = (int)pack2(fv[i].z, fv[i].w);                                \
            *reinterpret_cast<int2*>((DST) + dst) = v;                         \
        }                                                                      \
    }

#define GEMM_STEP(SRC)                                                         \
    _Pragma("unroll") for (int ks = 0; ks < 4; ++ks) {                         \
        bf16x8 a[2];                                                           \
        _Pragma("unroll") for (int mt = 0; mt < 2; ++mt) {                     \
            const uint32_t row = (uint32_t)(wr * 32 + mt * 16 + fr);           \
            a[mt] = *reinterpret_cast<const bf16x8*>(                          \
                (SRC) + row * 256u +                                           \
                (((uint32_t)(ks * 4 + h) ^ (row & 15u)) << 4));                \
        }                                                                      \
        _Pragma("unroll") for (int mt = 0; mt < 2; ++mt)                       \
            _Pragma("unroll") for (int nt = 0; nt < 4; ++nt)                   \
                acc[mt][nt] = __builtin_amdgcn_mfma_f32_16x16x32_bf16(         \
                    a[mt], bf[nt][ks], acc[mt][nt], 0, 0, 0);                  \
    }

#define DUMP_H(SO)                                                             \
    _Pragma("unroll") for (int nt = 0; nt < 4; ++nt) {                         \
        const int col = wc * 64 + nt * 16 + fr;                                \
        const float bv = bias[col];                                            \
        const int feat = (SO) + col;                                           \
        _Pragma("unroll") for (int mt = 0; mt < 2; ++mt) {                     \
            const int rowb = wr * 32 + mt * 16 + h * 4;                        \
            int2 o;                                                            \
            o.x = (int)pack2(acc[mt][nt][0] + bv, acc[mt][nt][1] + bv);        \
            o.y = (int)pack2(acc[mt][nt][2] + bv, acc[mt][nt][3] + bv);        \
            const uint32_t db = (uint32_t)feat * 128u +                        \
                ((uint32_t)((rowb >> 3) ^ (feat & 7)) << 4) +                  \
                (uint32_t)(rowb & 7) * 2u;                                     \
            *reinterpret_cast<int2*>(smHT + db) = o;                           \
            acc[mt][nt] = (f32x4){0.f, 0.f, 0.f, 0.f};                         \
        }                                                                      \
    }

// producer: expand 2 features (f0, f0+1) of step JB for row l into DST
#define EXPAND2(DST, JB)                                                       \
    _Pragma("unroll") for (int e = 0; e < 2; ++e) {                            \
        const int f = p * 2 + e;                                               \
        const int feat = (JB) * 8 + f;                                         \
        const unsigned short xv = *reinterpret_cast<const unsigned short*>(    \
            smHT + (uint32_t)feat * 128u +                                     \
            ((uint32_t)((l >> 3) ^ (feat & 7)) << 4) + (uint32_t)(l & 7) * 2u);\
        const float x = bf2f(xv);                                              \
        float bs[8];                                                           \
        bspline8(x, bs);                                                       \
        const uint32_t pw0 = pack2(silu_f(x), bs[0]);                          \
        const uint32_t pw1 = pack2(bs[1], bs[2]);                              \
        const uint32_t pw2 = pack2(bs[3], bs[4]);                              \
        const uint32_t pw3 = pack2(bs[5], bs[6]);                              \
        const uint32_t pw4 = pack2(bs[7], 0.f);                                \
        const uint32_t d0 = (uint32_t)l * 256u +                               \
            ((uint32_t)((2 * f) ^ (l & 15)) << 4);                             \
        const uint32_t d1 = (uint32_t)l * 256u +                               \
            ((uint32_t)((2 * f + 1) ^ (l & 15)) << 4);                         \
        *reinterpret_cast<int4*>((DST) + d0) =                                 \
            make_int4((int)pw0, (int)pw1, (int)pw2, (int)pw3);                 \
        *reinterpret_cast<int4*>((DST) + d1) = make_int4((int)pw4, 0, 0, 0);   \
    }

#define PH_BAR()                                                               \
    asm volatile("s_waitcnt lgkmcnt(0)" ::: "memory");                         \
    __builtin_amdgcn_sched_barrier(0);                                         \
    __builtin_amdgcn_s_barrier();                                              \
    __builtin_amdgcn_sched_barrier(0);

    // ================= Phase 1: feature transform (both sides) =============
    if (cons) { LOADF(WbF, 0); }
    else      { STAGE_A(buf0, 0); }
    PH_BAR();
#pragma unroll 1
    for (int tile = 0; tile < 12; ++tile) {
        char* cur = (tile & 1) ? buf1 : buf0;
        char* nxt = (tile & 1) ? buf0 : buf1;
        if (cons) {
            __builtin_amdgcn_s_setprio(1);
            GEMM_STEP(cur);
            __builtin_amdgcn_s_setprio(0);
            if (tile < 11) { LOADF(WbF, (tile + 1) % 6); }
            if (tile == 5) { DUMP_H(0); }
            if (tile == 11) { DUMP_H(128); }
        } else {
            if (tile < 11) { STAGE_A(nxt, tile + 1); }
        }
        PH_BAR();
    }

    // ================= Phase 2: KAN1 GEMM (K = 256*16) =====================
    if (cons) { LOADF(BpF, 0); }
    else      { EXPAND2(buf0, 0); }
    PH_BAR();
#pragma unroll 1
    for (int jb = 0; jb < 32; ++jb) {
        char* cur = (jb & 1) ? buf1 : buf0;
        char* nxt = (jb & 1) ? buf0 : buf1;
        if (cons) {
            __builtin_amdgcn_s_setprio(1);
            GEMM_STEP(cur);
            __builtin_amdgcn_s_setprio(0);
            if (jb < 31) { LOADF(BpF, jb + 1); }
        } else {
            if (jb < 31) { EXPAND2(nxt, jb + 1); }
        }
        PH_BAR();
    }

    // ================= Phase 3: KAN2 + sigmoid =============================
    unsigned short* smH2 = (unsigned short*)lds;   // [64][136] bf16 (17.4 KB)
    if (cons) {
#pragma unroll
        for (int mt = 0; mt < 2; ++mt)
#pragma unroll
            for (int nt = 0; nt < 4; ++nt) {
                const int col = wc * 64 + nt * 16 + fr;
#pragma unroll
                for (int j = 0; j < 4; ++j) {
                    const int row = wr * 32 + mt * 16 + h * 4 + j;
                    smH2[row * 136 + col] = f2bf(acc[mt][nt][j]);
                }
            }
    }
    __syncthreads();
    const int row2 = t >> 3, qd = t & 7;           // 8 threads/row, 16 cols each
    float sum = 0.f;
#pragma unroll 4
    for (int i = 0; i < 16; ++i) {
        const int j = qd * 16 + ((i + qd * 2) & 15);   // stagger banks
        const float x = bf2f(smH2[row2 * 136 + j]);
        float bs[8];
        bspline8(x, bs);
        const float4 s0 = *reinterpret_cast<const float4*>(&w2s[j * 8]);
        const float4 s1 = *reinterpret_cast<const float4*>(&w2s[j * 8 + 4]);
        float s = silu_f(x) * w2b[j];
        s += bs[0] * s0.x + bs[1] * s0.y + bs[2] * s0.z + bs[3] * s0.w;
        s += bs[4] * s1.x + bs[5] * s1.y + bs[6] * s1.z + bs[7] * s1.w;
        sum += s;
    }
    sum += __shfl_xor(sum, 1, 64);
    sum += __shfl_xor(sum, 2, 64);
    sum += __shfl_xor(sum, 4, 64);
    if (qd == 0) out[r0 + row2] = 1.0f / (1.0f + __expf(-sum));
}

// ---------------------------------------------------------------------------
extern "C" void kernel_launch(void* const* d_in, const int* in_sizes, int n_in,
                              void* d_out, int out_size, void* d_ws, size_t ws_size,
                              hipStream_t stream) {
    const float* stm  = (const float*)d_in[0];
    const float* nstm = (const float*)d_in[1];
    const float* ft_w = (const float*)d_in[2];
    const float* ft_b = (const float*)d_in[3];
    const float* k1bw = (const float*)d_in[4];
    const float* k1sw = (const float*)d_in[5];
    const float* k2bw = (const float*)d_in[6];
    const float* k2sw = (const float*)d_in[7];
    float* out = (float*)d_out;

    char* ws = (char*)d_ws;
    unsigned short* WbF = (unsigned short*)ws;                //   196,608 B
    unsigned short* BpF = (unsigned short*)(ws + 196608);     // 1,048,576 B

    prep_wbf<<<384, 256, 0, stream>>>(ft_w, WbF);
    prep_bpf<<<2048, 256, 0, stream>>>(k1bw, k1sw, BpF);
    kan_fused<<<512, 512, 0, stream>>>(stm, nstm, WbF, ft_b, BpF, k2bw, k2sw, out);
}

// Round 16
// 105.982 us; speedup vs baseline: 3.4335x; 3.4335x over previous
//
#include <hip/hip_runtime.h>
#include <hip/hip_bf16.h>
#include <math.h>
#include <stdint.h>

typedef __attribute__((ext_vector_type(8))) short bf16x8;
typedef __attribute__((ext_vector_type(4))) float f32x4;

__device__ __forceinline__ uint32_t pack2(float a, float b) {
    union { __hip_bfloat162 h2; uint32_t u; } c;
    c.h2 = __float22bfloat162_rn(make_float2(a, b));   // v_cvt_pk_bf16_f32
    return c.u;
}
__device__ __forceinline__ unsigned short f2bf(float f) {
    union { __hip_bfloat16 h; unsigned short u; } c;
    c.h = __float2bfloat16(f);
    return c.u;
}
__device__ __forceinline__ float bf2f(unsigned short h) {
    union { uint32_t u; float f; } c; c.u = ((uint32_t)h) << 16;
    return c.f;
}
__device__ __forceinline__ float silu_f(float x) {
    return x / (1.0f + __expf(-x));
}

// Uniform cardinal cubic B-spline bases on grid g_i = -2.2 + 0.4*i.
// Identical to the reference Cox-de-Boor recursion on this uniform grid.
__device__ __forceinline__ void bspline8(float x, float* __restrict__ b) {
    const float tt = (x + 2.2f) * 2.5f;
#pragma unroll
    for (int v = 0; v < 8; ++v) {
        float y = fabsf(tt - (float)(v + 2));
        float p = fmaxf(2.0f - y, 0.0f);
        float q = fmaxf(1.0f - y, 0.0f);
        b[v] = (p * p * p - 4.0f * q * q * q) * (1.0f / 6.0f);
    }
}

__device__ __forceinline__ void gload16(const void* g, void* l) {
    __builtin_amdgcn_global_load_lds(
        (const __attribute__((address_space(1))) void*)g,
        (__attribute__((address_space(3))) void*)l, 16, 0, 0);
}

// ---------------------------------------------------------------------------
// prep kernels
// ---------------------------------------------------------------------------
__global__ __launch_bounds__(256) void prep_ftw(const float* __restrict__ ftw,
                                                unsigned short* __restrict__ Wb) {
    const int idx = blockIdx.x * 256 + threadIdx.x;   // 98304 = 128*768
    Wb[idx] = f2bf(ftw[idx]);
}

__global__ __launch_bounds__(256) void prep_bp(const float* __restrict__ bw,
                                               const float* __restrict__ sw,
                                               unsigned short* __restrict__ Bp) {
    const int idx = blockIdx.x * 256 + threadIdx.x;   // 524288 = 128*4096
    const int n = idx >> 12;
    const int k = idx & 4095;
    const int f = k >> 4;
    const int v = k & 15;
    float val = 0.f;
    if (v == 0) val = bw[n * 256 + f];
    else if (v <= 8) val = sw[(size_t)(n * 256 + f) * 8 + (v - 1)];
    Bp[idx] = f2bf(val);
}

// ---------------------------------------------------------------------------
// FUSED, BM=64, 2 blocks/CU (LDS exactly 80 KB).  Per 64-row tile:
//   Phase 1: FT GEMM both sides (12 BK=128 tiles), depth-2 reg prefetch of A
//            (named reg sets, counted vmcnt(4)), Wb via gload_lds with
//            pre-swizzled source (rule 21).  H -> smHT (transposed
//            [256 feat][64 rows] bf16, chunk-XOR swizzled) -- LDS only.
//   Phase 2: KAN1 expanded-A GEMM, 32 jb-steps; Bp gloads issued first,
//            expansion VALU hides their L2 latency; conflict-free smHT read.
//   Phase 3: KAN2 reduce + sigmoid.
// grid 512, block 512 (8 waves as 2x4; wave tile 32r x 32c both GEMMs).
// ---------------------------------------------------------------------------
__global__ __launch_bounds__(512, 4) void kan_fused(
        const float* __restrict__ stm, const float* __restrict__ nstm,
        const unsigned short* __restrict__ Wb, const float* __restrict__ bias,
        const unsigned short* __restrict__ Bp,
        const float* __restrict__ w2b, const float* __restrict__ w2s,
        float* __restrict__ out) {
    __shared__ alignas(16) char lds[81920];
    char* smA  = lds;            // 16 KB: A/phi tile 64 x 128 bf16, swizzled
    char* smB  = lds + 16384;    // 32 KB: B tile 128 x 128 bf16, swizzled
    char* smHT = lds + 49152;    // 32 KB: H^T [256 feat][64 rows] bf16, swizzled

    const int r0 = blockIdx.x * 64;
    const int t = threadIdx.x;
    const int l = t & 63, w = t >> 6;
    const int fr = l & 15, h = l >> 4;
    const int wr = w >> 2, wc = w & 3;        // 2x4 wave grid, tile 32r x 32c

    // A staging geometry: thread -> row (t>>3), 16 floats at col (t&7)*16
    const int arow = t >> 3;
    const int acol = (t & 7) * 16;
    const uint32_t adst0 = (uint32_t)arow * 256u +
        ((uint32_t)(((t & 7) * 2) ^ (arow & 15)) << 4);
    const uint32_t adst1 = (uint32_t)arow * 256u +
        ((uint32_t)(((t & 7) * 2 + 1) ^ (arow & 15)) << 4);
    const int gidx = w * 4;                   // gload instr base index

    f32x4 acc[2][2];
#pragma unroll
    for (int mt = 0; mt < 2; ++mt)
#pragma unroll
        for (int nt = 0; nt < 2; ++nt) acc[mt][nt] = (f32x4){0.f, 0.f, 0.f, 0.f};

    float4 regY[4], regZ[4];

#define FT_ISSUE(REG, TK)                                                      \
    {                                                                          \
        const float* __restrict__ Ap = ((TK) >= 6) ? nstm : stm;               \
        const int kk = ((TK) % 6) * 128;                                       \
        _Pragma("unroll") for (int q = 0; q < 4; ++q)                          \
            REG[q] = *reinterpret_cast<const float4*>(                         \
                &Ap[(size_t)(r0 + arow) * 768 + kk + acol + q * 4]);           \
    }

#define FT_WRITE(REG)                                                          \
    {                                                                          \
        int4 w0, w1;                                                           \
        w0.x = (int)pack2(REG[0].x, REG[0].y);                                 \
        w0.y = (int)pack2(REG[0].z, REG[0].w);                                 \
        w0.z = (int)pack2(REG[1].x, REG[1].y);                                 \
        w0.w = (int)pack2(REG[1].z, REG[1].w);                                 \
        w1.x = (int)pack2(REG[2].x, REG[2].y);                                 \
        w1.y = (int)pack2(REG[2].z, REG[2].w);                                 \
        w1.z = (int)pack2(REG[3].x, REG[3].y);                                 \
        w1.w = (int)pack2(REG[3].z, REG[3].w);                                 \
        *reinterpret_cast<int4*>(smA + adst0) = w0;                            \
        *reinterpret_cast<int4*>(smA + adst1) = w1;                            \
    }

#define GLOADB_FT(K0)                                                          \
    _Pragma("unroll") for (int j = 0; j < 4; ++j) {                            \
        const int col = (gidx + j) * 4 + (l >> 4);                             \
        gload16(&Wb[(size_t)col * 768 + (K0) + (((l & 15) ^ (col & 15)) << 3)],\
                smB + (gidx + j) * 1024);                                      \
    }

#define GEMM_STEP()                                                            \
    _Pragma("unroll") for (int ks = 0; ks < 4; ++ks) {                         \
        bf16x8 a[2], b[2];                                                     \
        _Pragma("unroll") for (int mt = 0; mt < 2; ++mt) {                     \
            const uint32_t row = (uint32_t)(wr * 32 + mt * 16 + fr);           \
            a[mt] = *reinterpret_cast<const bf16x8*>(                          \
                smA + row * 256u +                                             \
                (((uint32_t)(ks * 4 + h) ^ (row & 15u)) << 4));                \
        }                                                                      \
        _Pragma("unroll") for (int nt = 0; nt < 2; ++nt) {                     \
            const uint32_t col = (uint32_t)(wc * 32 + nt * 16 + fr);           \
            b[nt] = *reinterpret_cast<const bf16x8*>(                          \
                smB + col * 256u +                                             \
                (((uint32_t)(ks * 4 + h) ^ (col & 15u)) << 4));                \
        }                                                                      \
        _Pragma("unroll") for (int mt = 0; mt < 2; ++mt)                       \
            _Pragma("unroll") for (int nt = 0; nt < 2; ++nt)                   \
                acc[mt][nt] = __builtin_amdgcn_mfma_f32_16x16x32_bf16(         \
                    a[mt], b[nt], acc[mt][nt], 0, 0, 0);                       \
    }

#define DUMP_H(SO)                                                             \
    _Pragma("unroll") for (int nt = 0; nt < 2; ++nt) {                         \
        const int col = wc * 32 + nt * 16 + fr;                                \
        const float bv = bias[col];                                            \
        const int feat = (SO) + col;                                           \
        _Pragma("unroll") for (int mt = 0; mt < 2; ++mt) {                     \
            const int rowb = wr * 32 + mt * 16 + h * 4;                        \
            int2 o;                                                            \
            o.x = (int)pack2(acc[mt][nt][0] + bv, acc[mt][nt][1] + bv);        \
            o.y = (int)pack2(acc[mt][nt][2] + bv, acc[mt][nt][3] + bv);        \
            const uint32_t db = (uint32_t)feat * 128u +                        \
                ((uint32_t)((rowb >> 3) ^ (feat & 7)) << 4) +                  \
                (uint32_t)(rowb & 7) * 2u;                                     \
            *reinterpret_cast<int2*>(smHT + db) = o;                           \
            acc[mt][nt] = (f32x4){0.f, 0.f, 0.f, 0.f};                         \
        }                                                                      \
    }

#define LGKM_BAR()                                                             \
    asm volatile("s_waitcnt lgkmcnt(0)" ::: "memory");                         \
    __builtin_amdgcn_sched_barrier(0);                                         \
    __builtin_amdgcn_s_barrier();

    // ================= Phase 1: feature transform (both sides) =============
    FT_ISSUE(regY, 0);
    FT_ISSUE(regZ, 1);
#pragma unroll 1
    for (int pp = 0; pp < 6; ++pp) {
        // ---- even slot: tile 2pp ----
        FT_WRITE(regY);                       // compiler waits regY's loads
        GLOADB_FT(((2 * pp) % 6) * 128);
        __builtin_amdgcn_sched_barrier(0);    // pin: B gloads older than A issue
        if (pp < 5) {
            FT_ISSUE(regY, 2 * pp + 2);
            asm volatile("s_waitcnt vmcnt(4)" ::: "memory");   // B done, A flying
        } else {
            asm volatile("s_waitcnt vmcnt(0)" ::: "memory");
        }
        asm volatile("s_waitcnt lgkmcnt(0)" ::: "memory");
        __builtin_amdgcn_sched_barrier(0);
        __builtin_amdgcn_s_barrier();
        __builtin_amdgcn_s_setprio(1);
        GEMM_STEP();
        __builtin_amdgcn_s_setprio(0);
        LGKM_BAR();
        // ---- odd slot: tile 2pp+1 ----
        FT_WRITE(regZ);
        GLOADB_FT(((2 * pp + 1) % 6) * 128);
        __builtin_amdgcn_sched_barrier(0);
        if (pp < 5) {
            FT_ISSUE(regZ, 2 * pp + 3);
            asm volatile("s_waitcnt vmcnt(4)" ::: "memory");
        } else {
            asm volatile("s_waitcnt vmcnt(0)" ::: "memory");
        }
        asm volatile("s_waitcnt lgkmcnt(0)" ::: "memory");
        __builtin_amdgcn_sched_barrier(0);
        __builtin_amdgcn_s_barrier();
        __builtin_amdgcn_s_setprio(1);
        GEMM_STEP();
        __builtin_amdgcn_s_setprio(0);
        if (pp == 2) { DUMP_H(0); }           // side 0 complete
        if (pp == 5) { DUMP_H(128); }         // side 1 complete
        LGKM_BAR();
    }

    // ================= Phase 2: KAN1 GEMM (K = 256*16) =====================
#pragma unroll 1
    for (int jb = 0; jb < 32; ++jb) {
        // 1. Bp tile gloads first (L2 latency hides under expansion VALU)
#pragma unroll
        for (int j = 0; j < 4; ++j) {
            const int col = (gidx + j) * 4 + (l >> 4);
            gload16(&Bp[(size_t)col * 4096 + jb * 128 +
                        (((l & 15) ^ (col & 15)) << 3)],
                    smB + (gidx + j) * 1024);
        }
        __builtin_amdgcn_sched_barrier(0);
        // 2. expansion: wave w -> feature jb*8+w, lane l -> row l
        {
            const int feat = jb * 8 + w;
            const unsigned short xv = *reinterpret_cast<const unsigned short*>(
                smHT + (uint32_t)feat * 128u +
                ((uint32_t)((l >> 3) ^ (feat & 7)) << 4) + (uint32_t)(l & 7) * 2u);
            const float x = bf2f(xv);
            float bs[8];
            bspline8(x, bs);
            const uint32_t pw0 = pack2(silu_f(x), bs[0]);
            const uint32_t pw1 = pack2(bs[1], bs[2]);
            const uint32_t pw2 = pack2(bs[3], bs[4]);
            const uint32_t pw3 = pack2(bs[5], bs[6]);
            const uint32_t pw4 = pack2(bs[7], 0.f);
            const uint32_t d0 = (uint32_t)l * 256u +
                ((uint32_t)((2 * w) ^ (l & 15)) << 4);
            const uint32_t d1 = (uint32_t)l * 256u +
                ((uint32_t)((2 * w + 1) ^ (l & 15)) << 4);
            *reinterpret_cast<int4*>(smA + d0) =
                make_int4((int)pw0, (int)pw1, (int)pw2, (int)pw3);
            *reinterpret_cast<int4*>(smA + d1) = make_int4((int)pw4, 0, 0, 0);
        }
        asm volatile("s_waitcnt vmcnt(0) lgkmcnt(0)" ::: "memory");
        __builtin_amdgcn_sched_barrier(0);
        __builtin_amdgcn_s_barrier();
        __builtin_amdgcn_s_setprio(1);
        GEMM_STEP();
        __builtin_amdgcn_s_setprio(0);
        LGKM_BAR();
    }

    // ================= Phase 3: KAN2 + sigmoid =============================
    unsigned short* smH2 = (unsigned short*)lds;   // reuse smA/smB region
#pragma unroll
    for (int mt = 0; mt < 2; ++mt)
#pragma unroll
        for (int nt = 0; nt < 2; ++nt) {
            const int col = wc * 32 + nt * 16 + fr;
#pragma unroll
            for (int j = 0; j < 4; ++j) {
                const int row = wr * 32 + mt * 16 + h * 4 + j;
                smH2[row * 136 + col] = f2bf(acc[mt][nt][j]);
            }
        }
    __syncthreads();
    const int row2 = t >> 3, qd = t & 7;           // 8 threads/row, 16 cols each
    float sum = 0.f;
#pragma unroll 4
    for (int i = 0; i < 16; ++i) {
        const int j = qd * 16 + ((i + qd * 2) & 15);   // stagger banks
        const float x = bf2f(smH2[row2 * 136 + j]);
        float bs[8];
        bspline8(x, bs);
        const float4 s0 = *reinterpret_cast<const float4*>(&w2s[j * 8]);
        const float4 s1 = *reinterpret_cast<const float4*>(&w2s[j * 8 + 4]);
        float s = silu_f(x) * w2b[j];
        s += bs[0] * s0.x + bs[1] * s0.y + bs[2] * s0.z + bs[3] * s0.w;
        s += bs[4] * s1.x + bs[5] * s1.y + bs[6] * s1.z + bs[7] * s1.w;
        sum += s;
    }
    sum += __shfl_xor(sum, 1, 64);
    sum += __shfl_xor(sum, 2, 64);
    sum += __shfl_xor(sum, 4, 64);
    if (qd == 0) out[r0 + row2] = 1.0f / (1.0f + __expf(-sum));
}

// ---------------------------------------------------------------------------
extern "C" void kernel_launch(void* const* d_in, const int* in_sizes, int n_in,
                              void* d_out, int out_size, void* d_ws, size_t ws_size,
                              hipStream_t stream) {
    const float* stm  = (const float*)d_in[0];
    const float* nstm = (const float*)d_in[1];
    const float* ft_w = (const float*)d_in[2];
    const float* ft_b = (const float*)d_in[3];
    const float* k1bw = (const float*)d_in[4];
    const float* k1sw = (const float*)d_in[5];
    const float* k2bw = (const float*)d_in[6];
    const float* k2sw = (const float*)d_in[7];
    float* out = (float*)d_out;

    char* ws = (char*)d_ws;
    unsigned short* Wb = (unsigned short*)ws;                 //   196,608 B
    unsigned short* Bp = (unsigned short*)(ws + 196608);      // 1,048,576 B

    prep_ftw<<<384, 256, 0, stream>>>(ft_w, Wb);
    prep_bp<<<2048, 256, 0, stream>>>(k1bw, k1sw, Bp);
    kan_fused<<<512, 512, 0, stream>>>(stm, nstm, Wb, ft_b, Bp, k2bw, k2sw, out);
}

// Round 17
// 104.172 us; speedup vs baseline: 3.4931x; 1.0174x over previous
//
#include <hip/hip_runtime.h>
#include <hip/hip_bf16.h>
#include <math.h>
#include <stdint.h>

typedef __attribute__((ext_vector_type(8))) short bf16x8;
typedef __attribute__((ext_vector_type(4))) float f32x4;

__device__ __forceinline__ uint32_t pack2(float a, float b) {
    union { __hip_bfloat162 h2; uint32_t u; } c;
    c.h2 = __float22bfloat162_rn(make_float2(a, b));   // v_cvt_pk_bf16_f32
    return c.u;
}
__device__ __forceinline__ unsigned short f2bf(float f) {
    union { __hip_bfloat16 h; unsigned short u; } c;
    c.h = __float2bfloat16(f);
    return c.u;
}
__device__ __forceinline__ float bf2f(unsigned short h) {
    union { uint32_t u; float f; } c; c.u = ((uint32_t)h) << 16;
    return c.f;
}
__device__ __forceinline__ float silu_f(float x) {
    return x / (1.0f + __expf(-x));
}

// Uniform cardinal cubic B-spline bases on grid g_i = -2.2 + 0.4*i.
// Identical to the reference Cox-de-Boor recursion on this uniform grid.
__device__ __forceinline__ void bspline8(float x, float* __restrict__ b) {
    const float tt = (x + 2.2f) * 2.5f;
#pragma unroll
    for (int v = 0; v < 8; ++v) {
        float y = fabsf(tt - (float)(v + 2));
        float p = fmaxf(2.0f - y, 0.0f);
        float q = fmaxf(1.0f - y, 0.0f);
        b[v] = (p * p * p - 4.0f * q * q * q) * (1.0f / 6.0f);
    }
}

__device__ __forceinline__ void gload16(const void* g, void* l) {
    __builtin_amdgcn_global_load_lds(
        (const __attribute__((address_space(1))) void*)g,
        (__attribute__((address_space(3))) void*)l, 16, 0, 0);
}

// ---------------------------------------------------------------------------
// prep kernels
// ---------------------------------------------------------------------------
__global__ __launch_bounds__(256) void prep_ftw(const float* __restrict__ ftw,
                                                unsigned short* __restrict__ Wb) {
    const int idx = blockIdx.x * 256 + threadIdx.x;   // 98304 = 128*768
    Wb[idx] = f2bf(ftw[idx]);
}

// Bp -> fragment-contiguous bf16: [jb(32)][wc(4)][nt(2)][ks(4)][l(64)][e(8)]
//   col = wc*32 + nt*16 + (l&15);  k = jb*128 + ks*32 + (l>>4)*8 + e
__global__ __launch_bounds__(256) void prep_bpf(const float* __restrict__ bw,
                                                const float* __restrict__ sw,
                                                unsigned short* __restrict__ BpF) {
    const int idx = blockIdx.x * 256 + threadIdx.x;   // 524288 = 32*16384
    const int e = idx & 7, l = (idx >> 3) & 63, ks = (idx >> 9) & 3;
    const int nt = (idx >> 11) & 1, wc = (idx >> 12) & 3, jb = idx >> 14;
    const int col = wc * 32 + nt * 16 + (l & 15);
    const int k = jb * 128 + ks * 32 + (l >> 4) * 8 + e;
    const int f = k >> 4, v = k & 15;
    float val = 0.f;
    if (v == 0) val = bw[col * 256 + f];
    else if (v <= 8) val = sw[(size_t)(col * 256 + f) * 8 + (v - 1)];
    BpF[idx] = f2bf(val);
}

// ---------------------------------------------------------------------------
// FUSED, BM=64, 2 blocks/CU (LDS 80 KB).  Per 64-row tile:
//   Phase 1: FT GEMM both sides (12 BK=128 tiles), depth-2 reg prefetch of A
//            (named reg sets, counted vmcnt(4)), Wb via gload_lds with
//            pre-swizzled source.  H -> smHT (transposed [256][64] bf16,
//            chunk-XOR swizzled) -- LDS only.      [identical to round 11]
//   Phase 2: KAN1 expanded-A GEMM, 32 jb-steps; Bp FRAGMENT-CONTIGUOUS
//            direct global->reg (issued before expansion; L2 latency hides
//            under the ~110-op spline VALU).  NO b-side LDS reads, NO smB
//            staging, NO vmcnt drains in this phase.
//   Phase 3: KAN2 reduce + sigmoid.
// grid 512, block 512 (8 waves as 2x4; wave tile 32r x 32c both GEMMs).
// ---------------------------------------------------------------------------
__global__ __launch_bounds__(512, 4) void kan_fused(
        const float* __restrict__ stm, const float* __restrict__ nstm,
        const unsigned short* __restrict__ Wb, const float* __restrict__ bias,
        const unsigned short* __restrict__ BpF,
        const float* __restrict__ w2b, const float* __restrict__ w2s,
        float* __restrict__ out) {
    __shared__ alignas(16) char lds[81920];
    char* smA  = lds;            // 16 KB: A/phi tile 64 x 128 bf16, swizzled
    char* smB  = lds + 16384;    // 32 KB: ph1 Wb tile 128 x 128 bf16, swizzled
    char* smHT = lds + 49152;    // 32 KB: H^T [256 feat][64 rows] bf16, swizzled

    const int r0 = blockIdx.x * 64;
    const int t = threadIdx.x;
    const int l = t & 63, w = t >> 6;
    const int fr = l & 15, h = l >> 4;
    const int wr = w >> 2, wc = w & 3;        // 2x4 wave grid, tile 32r x 32c

    // A staging geometry: thread -> row (t>>3), 16 floats at col (t&7)*16
    const int arow = t >> 3;
    const int acol = (t & 7) * 16;
    const uint32_t adst0 = (uint32_t)arow * 256u +
        ((uint32_t)(((t & 7) * 2) ^ (arow & 15)) << 4);
    const uint32_t adst1 = (uint32_t)arow * 256u +
        ((uint32_t)(((t & 7) * 2 + 1) ^ (arow & 15)) << 4);
    const int gidx = w * 4;                   // gload instr base index

    f32x4 acc[2][2];
#pragma unroll
    for (int mt = 0; mt < 2; ++mt)
#pragma unroll
        for (int nt = 0; nt < 2; ++nt) acc[mt][nt] = (f32x4){0.f, 0.f, 0.f, 0.f};

    float4 regY[4], regZ[4];
    bf16x8 bf[2][4];   // phase-2 B fragments (static indexing only)

#define FT_ISSUE(REG, TK)                                                      \
    {                                                                          \
        const float* __restrict__ Ap = ((TK) >= 6) ? nstm : stm;               \
        const int kk = ((TK) % 6) * 128;                                       \
        _Pragma("unroll") for (int q = 0; q < 4; ++q)                          \
            REG[q] = *reinterpret_cast<const float4*>(                         \
                &Ap[(size_t)(r0 + arow) * 768 + kk + acol + q * 4]);           \
    }

#define FT_WRITE(REG)                                                          \
    {                                                                          \
        int4 w0, w1;                                                           \
        w0.x = (int)pack2(REG[0].x, REG[0].y);                                 \
        w0.y = (int)pack2(REG[0].z, REG[0].w);                                 \
        w0.z = (int)pack2(REG[1].x, REG[1].y);                                 \
        w0.w = (int)pack2(REG[1].z, REG[1].w);                                 \
        w1.x = (int)pack2(REG[2].x, REG[2].y);                                 \
        w1.y = (int)pack2(REG[2].z, REG[2].w);                                 \
        w1.z = (int)pack2(REG[3].x, REG[3].y);                                 \
        w1.w = (int)pack2(REG[3].z, REG[3].w);                                 \
        *reinterpret_cast<int4*>(smA + adst0) = w0;                            \
        *reinterpret_cast<int4*>(smA + adst1) = w1;                            \
    }

#define GLOADB_FT(K0)                                                          \
    _Pragma("unroll") for (int j = 0; j < 4; ++j) {                            \
        const int col = (gidx + j) * 4 + (l >> 4);                             \
        gload16(&Wb[(size_t)col * 768 + (K0) + (((l & 15) ^ (col & 15)) << 3)],\
                smB + (gidx + j) * 1024);                                      \
    }

// phase-2: B fragments, one fully-coalesced 1 KB load per (nt,ks)
#define LOADF(JB)                                                              \
    {                                                                          \
        const unsigned short* __restrict__ fb =                                \
            BpF + (size_t)(JB) * 16384 + wc * 4096 + l * 8;                    \
        _Pragma("unroll") for (int nt = 0; nt < 2; ++nt)                       \
            _Pragma("unroll") for (int ks = 0; ks < 4; ++ks)                   \
                bf[nt][ks] = *reinterpret_cast<const bf16x8*>(                 \
                    fb + nt * 2048 + ks * 512);                                \
    }

#define GEMM_STEP_LDS()                                                        \
    _Pragma("unroll") for (int ks = 0; ks < 4; ++ks) {                         \
        bf16x8 a[2], b[2];                                                     \
        _Pragma("unroll") for (int mt = 0; mt < 2; ++mt) {                     \
            const uint32_t row = (uint32_t)(wr * 32 + mt * 16 + fr);           \
            a[mt] = *reinterpret_cast<const bf16x8*>(                          \
                smA + row * 256u +                                             \
                (((uint32_t)(ks * 4 + h) ^ (row & 15u)) << 4));                \
        }                                                                      \
        _Pragma("unroll") for (int nt = 0; nt < 2; ++nt) {                     \
            const uint32_t col = (uint32_t)(wc * 32 + nt * 16 + fr);           \
            b[nt] = *reinterpret_cast<const bf16x8*>(                          \
                smB + col * 256u +                                             \
                (((uint32_t)(ks * 4 + h) ^ (col & 15u)) << 4));                \
        }                                                                      \
        _Pragma("unroll") for (int mt = 0; mt < 2; ++mt)                       \
            _Pragma("unroll") for (int nt = 0; nt < 2; ++nt)                   \
                acc[mt][nt] = __builtin_amdgcn_mfma_f32_16x16x32_bf16(         \
                    a[mt], b[nt], acc[mt][nt], 0, 0, 0);                       \
    }

#define GEMM_STEP_REG()                                                        \
    _Pragma("unroll") for (int ks = 0; ks < 4; ++ks) {                         \
        bf16x8 a[2];                                                           \
        _Pragma("unroll") for (int mt = 0; mt < 2; ++mt) {                     \
            const uint32_t row = (uint32_t)(wr * 32 + mt * 16 + fr);           \
            a[mt] = *reinterpret_cast<const bf16x8*>(                          \
                smA + row * 256u +                                             \
                (((uint32_t)(ks * 4 + h) ^ (row & 15u)) << 4));                \
        }                                                                      \
        _Pragma("unroll") for (int mt = 0; mt < 2; ++mt)                       \
            _Pragma("unroll") for (int nt = 0; nt < 2; ++nt)                   \
                acc[mt][nt] = __builtin_amdgcn_mfma_f32_16x16x32_bf16(         \
                    a[mt], bf[nt][ks], acc[mt][nt], 0, 0, 0);                  \
    }

#define DUMP_H(SO)                                                             \
    _Pragma("unroll") for (int nt = 0; nt < 2; ++nt) {                         \
        const int col = wc * 32 + nt * 16 + fr;                                \
        const float bv = bias[col];                                            \
        const int feat = (SO) + col;                                           \
        _Pragma("unroll") for (int mt = 0; mt < 2; ++mt) {                     \
            const int rowb = wr * 32 + mt * 16 + h * 4;                        \
            int2 o;                                                            \
            o.x = (int)pack2(acc[mt][nt][0] + bv, acc[mt][nt][1] + bv);        \
            o.y = (int)pack2(acc[mt][nt][2] + bv, acc[mt][nt][3] + bv);        \
            const uint32_t db = (uint32_t)feat * 128u +                        \
                ((uint32_t)((rowb >> 3) ^ (feat & 7)) << 4) +                  \
                (uint32_t)(rowb & 7) * 2u;                                     \
            *reinterpret_cast<int2*>(smHT + db) = o;                           \
            acc[mt][nt] = (f32x4){0.f, 0.f, 0.f, 0.f};                         \
        }                                                                      \
    }

#define LGKM_BAR()                                                             \
    asm volatile("s_waitcnt lgkmcnt(0)" ::: "memory");                         \
    __builtin_amdgcn_sched_barrier(0);                                         \
    __builtin_amdgcn_s_barrier();

    // ================= Phase 1: feature transform (both sides) =============
    FT_ISSUE(regY, 0);
    FT_ISSUE(regZ, 1);
#pragma unroll 1
    for (int pp = 0; pp < 6; ++pp) {
        // ---- even slot: tile 2pp ----
        FT_WRITE(regY);                       // compiler waits regY's loads
        GLOADB_FT(((2 * pp) % 6) * 128);
        __builtin_amdgcn_sched_barrier(0);    // pin: B gloads older than A issue
        if (pp < 5) {
            FT_ISSUE(regY, 2 * pp + 2);
            asm volatile("s_waitcnt vmcnt(4)" ::: "memory");   // B done, A flying
        } else {
            asm volatile("s_waitcnt vmcnt(0)" ::: "memory");
        }
        asm volatile("s_waitcnt lgkmcnt(0)" ::: "memory");
        __builtin_amdgcn_sched_barrier(0);
        __builtin_amdgcn_s_barrier();
        __builtin_amdgcn_s_setprio(1);
        GEMM_STEP_LDS();
        __builtin_amdgcn_s_setprio(0);
        LGKM_BAR();
        // ---- odd slot: tile 2pp+1 ----
        FT_WRITE(regZ);
        GLOADB_FT(((2 * pp + 1) % 6) * 128);
        __builtin_amdgcn_sched_barrier(0);
        if (pp < 5) {
            FT_ISSUE(regZ, 2 * pp + 3);
            asm volatile("s_waitcnt vmcnt(4)" ::: "memory");
        } else {
            asm volatile("s_waitcnt vmcnt(0)" ::: "memory");
        }
        asm volatile("s_waitcnt lgkmcnt(0)" ::: "memory");
        __builtin_amdgcn_sched_barrier(0);
        __builtin_amdgcn_s_barrier();
        __builtin_amdgcn_s_setprio(1);
        GEMM_STEP_LDS();
        __builtin_amdgcn_s_setprio(0);
        if (pp == 2) { DUMP_H(0); }           // side 0 complete
        if (pp == 5) { DUMP_H(128); }         // side 1 complete
        LGKM_BAR();
    }

    // ================= Phase 2: KAN1 GEMM (K = 256*16) =====================
#pragma unroll 1
    for (int jb = 0; jb < 32; ++jb) {
        // 1. Bp fragments -> regs (issued first; L2 latency hides under VALU)
        LOADF(jb);
        __builtin_amdgcn_sched_barrier(0);
        // 2. expansion: wave w -> feature jb*8+w, lane l -> row l
        {
            const int feat = jb * 8 + w;
            const unsigned short xv = *reinterpret_cast<const unsigned short*>(
                smHT + (uint32_t)feat * 128u +
                ((uint32_t)((l >> 3) ^ (feat & 7)) << 4) + (uint32_t)(l & 7) * 2u);
            const float x = bf2f(xv);
            float bs[8];
            bspline8(x, bs);
            const uint32_t pw0 = pack2(silu_f(x), bs[0]);
            const uint32_t pw1 = pack2(bs[1], bs[2]);
            const uint32_t pw2 = pack2(bs[3], bs[4]);
            const uint32_t pw3 = pack2(bs[5], bs[6]);
            const uint32_t pw4 = pack2(bs[7], 0.f);
            const uint32_t d0 = (uint32_t)l * 256u +
                ((uint32_t)((2 * w) ^ (l & 15)) << 4);
            const uint32_t d1 = (uint32_t)l * 256u +
                ((uint32_t)((2 * w + 1) ^ (l & 15)) << 4);
            *reinterpret_cast<int4*>(smA + d0) =
                make_int4((int)pw0, (int)pw1, (int)pw2, (int)pw3);
            *reinterpret_cast<int4*>(smA + d1) = make_int4((int)pw4, 0, 0, 0);
        }
        asm volatile("s_waitcnt lgkmcnt(0)" ::: "memory");
        __builtin_amdgcn_sched_barrier(0);
        __builtin_amdgcn_s_barrier();
        __builtin_amdgcn_s_setprio(1);
        GEMM_STEP_REG();
        __builtin_amdgcn_s_setprio(0);
        LGKM_BAR();
    }

    // ================= Phase 3: KAN2 + sigmoid =============================
    unsigned short* smH2 = (unsigned short*)lds;   // reuse smA/smB region
#pragma unroll
    for (int mt = 0; mt < 2; ++mt)
#pragma unroll
        for (int nt = 0; nt < 2; ++nt) {
            const int col = wc * 32 + nt * 16 + fr;
#pragma unroll
            for (int j = 0; j < 4; ++j) {
                const int row = wr * 32 + mt * 16 + h * 4 + j;
                smH2[row * 136 + col] = f2bf(acc[mt][nt][j]);
            }
        }
    __syncthreads();
    const int row2 = t >> 3, qd = t & 7;           // 8 threads/row, 16 cols each
    float sum = 0.f;
#pragma unroll 4
    for (int i = 0; i < 16; ++i) {
        const int j = qd * 16 + ((i + qd * 2) & 15);   // stagger banks
        const float x = bf2f(smH2[row2 * 136 + j]);
        float bs[8];
        bspline8(x, bs);
        const float4 s0 = *reinterpret_cast<const float4*>(&w2s[j * 8]);
        const float4 s1 = *reinterpret_cast<const float4*>(&w2s[j * 8 + 4]);
        float s = silu_f(x) * w2b[j];
        s += bs[0] * s0.x + bs[1] * s0.y + bs[2] * s0.z + bs[3] * s0.w;
        s += bs[4] * s1.x + bs[5] * s1.y + bs[6] * s1.z + bs[7] * s1.w;
        sum += s;
    }
    sum += __shfl_xor(sum, 1, 64);
    sum += __shfl_xor(sum, 2, 64);
    sum += __shfl_xor(sum, 4, 64);
    if (qd == 0) out[r0 + row2] = 1.0f / (1.0f + __expf(-sum));
}

// ---------------------------------------------------------------------------
extern "C" void kernel_launch(void* const* d_in, const int* in_sizes, int n_in,
                              void* d_out, int out_size, void* d_ws, size_t ws_size,
                              hipStream_t stream) {
    const float* stm  = (const float*)d_in[0];
    const float* nstm = (const float*)d_in[1];
    const float* ft_w = (const float*)d_in[2];
    const float* ft_b = (const float*)d_in[3];
    const float* k1bw = (const float*)d_in[4];
    const float* k1sw = (const float*)d_in[5];
    const float* k2bw = (const float*)d_in[6];
    const float* k2sw = (const float*)d_in[7];
    float* out = (float*)d_out;

    char* ws = (char*)d_ws;
    unsigned short* Wb  = (unsigned short*)ws;                //   196,608 B
    unsigned short* BpF = (unsigned short*)(ws + 196608);     // 1,048,576 B

    prep_ftw<<<384, 256, 0, stream>>>(ft_w, Wb);
    prep_bpf<<<2048, 256, 0, stream>>>(k1bw, k1sw, BpF);
    kan_fused<<<512, 512, 0, stream>>>(stm, nstm, Wb, ft_b, BpF, k2bw, k2sw, out);
}